// Round 5
// baseline (501.062 us; speedup 1.0000x reference)
//
#include <hip/hip_runtime.h>
#include <hip/hip_bf16.h>
#include <cstdint>

typedef __bf16 bf16;
typedef bf16 bf16x8 __attribute__((ext_vector_type(8)));
typedef float f32x4 __attribute__((ext_vector_type(4)));

#define MFMA16(a, b, c) __builtin_amdgcn_mfma_f32_16x16x32_bf16((a), (b), (c), 0, 0, 0)

constexpr int D_MODEL = 768;
constexpr int NHEAD = 12;
constexpr int DK = 64;
constexpr int SEQ = 4096;
constexpr int BATCH = 2;
constexpr int MROWS = BATCH * SEQ;  // 8192
constexpr float QSCALE = 0.125f * 1.44269504089f;  // (1/sqrt(dk)) * log2(e)

// ---------------------------------------------------------------- convert x
__global__ void cvt_f32_to_bf16(const float* __restrict__ in, bf16* __restrict__ out, int n) {
    int i = (blockIdx.x * blockDim.x + threadIdx.x) * 4;
    if (i + 3 < n) {
        const float4 v = *reinterpret_cast<const float4*>(in + i);
        bf16 o0 = (bf16)v.x, o1 = (bf16)v.y, o2 = (bf16)v.z, o3 = (bf16)v.w;
        bf16 o[4] = {o0, o1, o2, o3};
        *reinterpret_cast<uint64_t*>(out + i) = *reinterpret_cast<uint64_t*>(o);
    }
}

// ---------------------------------------------------------------- fused QKV projection
// (verbatim from the passed 333us run)
__global__ __launch_bounds__(256, 2) void gemm_qkv(const bf16* __restrict__ A,
                                                   const float* __restrict__ Wq,
                                                   const float* __restrict__ Wk,
                                                   const float* __restrict__ Wv,
                                                   const float* __restrict__ bq,
                                                   const float* __restrict__ bk,
                                                   const float* __restrict__ bv,
                                                   bf16* __restrict__ Qb,
                                                   bf16* __restrict__ Kb,
                                                   bf16* __restrict__ Vtb) {
    constexpr int LDP = 88;
    __shared__ bf16 Asm[128][LDP];
    __shared__ bf16 Bsm[64][LDP];
    const int tid = threadIdx.x, lane = tid & 63, wid = tid >> 6;
    const int wm = wid >> 1, wn = wid & 1;
    const int m0 = blockIdx.x * 128;
    const int sel = blockIdx.y / 12;
    const int n0 = (blockIdx.y % 12) * 64;
    const float* Bw = sel == 0 ? Wq : (sel == 1 ? Wk : Wv);
    const float* bias = sel == 0 ? bq : (sel == 1 ? bk : bv);

    f32x4 acc[4][2];
#pragma unroll
    for (int i = 0; i < 4; i++)
#pragma unroll
        for (int j = 0; j < 2; j++) acc[i][j] = f32x4{0.f, 0.f, 0.f, 0.f};

    const int rr = tid >> 3, cc = (tid & 7) * 8;
    for (int k0 = 0; k0 < 768; k0 += 64) {
#pragma unroll
        for (int p = 0; p < 4; p++)
            *reinterpret_cast<bf16x8*>(&Asm[p * 32 + rr][cc]) =
                *reinterpret_cast<const bf16x8*>(A + (size_t)(m0 + p * 32 + rr) * 768 + k0 + cc);
#pragma unroll
        for (int p = 0; p < 2; p++) {
            const float* src = Bw + (size_t)(n0 + p * 32 + rr) * 768 + k0 + cc;
            const float4 f0 = *reinterpret_cast<const float4*>(src);
            const float4 f1 = *reinterpret_cast<const float4*>(src + 4);
            bf16x8 b8;
            b8[0] = (bf16)f0.x; b8[1] = (bf16)f0.y; b8[2] = (bf16)f0.z; b8[3] = (bf16)f0.w;
            b8[4] = (bf16)f1.x; b8[5] = (bf16)f1.y; b8[6] = (bf16)f1.z; b8[7] = (bf16)f1.w;
            *reinterpret_cast<bf16x8*>(&Bsm[p * 32 + rr][cc]) = b8;
        }
        __syncthreads();
#pragma unroll
        for (int kk = 0; kk < 64; kk += 32) {
            const int krd = kk + ((lane >> 4) << 3);
            bf16x8 af[4], bfr[2];
#pragma unroll
            for (int i = 0; i < 4; i++)
                af[i] = *reinterpret_cast<const bf16x8*>(&Asm[wm * 64 + i * 16 + (lane & 15)][krd]);
#pragma unroll
            for (int j = 0; j < 2; j++)
                bfr[j] = *reinterpret_cast<const bf16x8*>(&Bsm[wn * 32 + j * 16 + (lane & 15)][krd]);
#pragma unroll
            for (int i = 0; i < 4; i++)
#pragma unroll
                for (int j = 0; j < 2; j++) acc[i][j] = MFMA16(af[i], bfr[j], acc[i][j]);
        }
        __syncthreads();
    }

    const float scale = (sel == 0) ? QSCALE : 1.0f;
    const int rbase = m0 + wm * 64 + ((lane >> 4) << 2);
    const int cbase = n0 + wn * 32 + (lane & 15);
    bf16* obf = sel == 0 ? Qb : (sel == 1 ? Kb : Vtb);
#pragma unroll
    for (int i = 0; i < 4; i++) {
#pragma unroll
        for (int j = 0; j < 2; j++) {
            const int ncol = cbase + j * 16;
            const float bv = bias[ncol];
            const int h = ncol >> 6, d = ncol & 63;
#pragma unroll
            for (int r = 0; r < 4; r++) {
                const int mrow = rbase + i * 16 + r;
                const float v = (acc[i][j][r] + bv) * scale;
                const int b = mrow >> 12, s = mrow & 4095;
                if (sel < 2) {
                    obf[(((size_t)(b * NHEAD + h)) * SEQ + s) * DK + d] = (bf16)v;
                } else {
                    obf[(((size_t)(b * NHEAD + h)) * DK + d) * SEQ + s] = (bf16)v;
                }
            }
        }
    }
}

// ---------------------------------------------------------------- out projection GEMM
// (verbatim from the passed run)
__global__ __launch_bounds__(256, 2) void gemm_out(const bf16* __restrict__ A,
                                                   const float* __restrict__ Bw,
                                                   const float* __restrict__ bias,
                                                   float* __restrict__ ofl) {
    constexpr int LDP = 88;
    __shared__ bf16 Asm[128][LDP];
    __shared__ bf16 Bsm[64][LDP];
    const int tid = threadIdx.x, lane = tid & 63, wid = tid >> 6;
    const int wm = wid >> 1, wn = wid & 1;
    const int m0 = blockIdx.x * 128, n0 = blockIdx.y * 64;

    f32x4 acc[4][2];
#pragma unroll
    for (int i = 0; i < 4; i++)
#pragma unroll
        for (int j = 0; j < 2; j++) acc[i][j] = f32x4{0.f, 0.f, 0.f, 0.f};

    const int rr = tid >> 3, cc = (tid & 7) * 8;
    for (int k0 = 0; k0 < 768; k0 += 64) {
#pragma unroll
        for (int p = 0; p < 4; p++)
            *reinterpret_cast<bf16x8*>(&Asm[p * 32 + rr][cc]) =
                *reinterpret_cast<const bf16x8*>(A + (size_t)(m0 + p * 32 + rr) * 768 + k0 + cc);
#pragma unroll
        for (int p = 0; p < 2; p++) {
            const float* src = Bw + (size_t)(n0 + p * 32 + rr) * 768 + k0 + cc;
            const float4 f0 = *reinterpret_cast<const float4*>(src);
            const float4 f1 = *reinterpret_cast<const float4*>(src + 4);
            bf16x8 b8;
            b8[0] = (bf16)f0.x; b8[1] = (bf16)f0.y; b8[2] = (bf16)f0.z; b8[3] = (bf16)f0.w;
            b8[4] = (bf16)f1.x; b8[5] = (bf16)f1.y; b8[6] = (bf16)f1.z; b8[7] = (bf16)f1.w;
            *reinterpret_cast<bf16x8*>(&Bsm[p * 32 + rr][cc]) = b8;
        }
        __syncthreads();
#pragma unroll
        for (int kk = 0; kk < 64; kk += 32) {
            const int krd = kk + ((lane >> 4) << 3);
            bf16x8 af[4], bfr[2];
#pragma unroll
            for (int i = 0; i < 4; i++)
                af[i] = *reinterpret_cast<const bf16x8*>(&Asm[wm * 64 + i * 16 + (lane & 15)][krd]);
#pragma unroll
            for (int j = 0; j < 2; j++)
                bfr[j] = *reinterpret_cast<const bf16x8*>(&Bsm[wn * 32 + j * 16 + (lane & 15)][krd]);
#pragma unroll
            for (int i = 0; i < 4; i++)
#pragma unroll
                for (int j = 0; j < 2; j++) acc[i][j] = MFMA16(af[i], bfr[j], acc[i][j]);
        }
        __syncthreads();
    }

    const int rbase = m0 + wm * 64 + ((lane >> 4) << 2);
    const int cbase = n0 + wn * 32 + (lane & 15);
#pragma unroll
    for (int i = 0; i < 4; i++) {
#pragma unroll
        for (int j = 0; j < 2; j++) {
            const int ncol = cbase + j * 16;
            const float bv = bias[ncol];
#pragma unroll
            for (int r = 0; r < 4; r++) {
                const int mrow = rbase + i * 16 + r;
                ofl[(size_t)mrow * 768 + ncol] = acc[i][j][r] + bv;
            }
        }
    }
}

// ---------------------------------------------------------------- flash attention
// Proven 16x16 fabric (passed at 272us/4.9e-4) + occupancy/prefetch/swizzle upgrades:
//   - Psm re-phased to 32-key chunks: LDS 54.3KB -> 46KB => 3 blocks/CU
//   - next K/V tile prefetched into registers (lands under QK^T+softmax)
//   - XCD-swizzled 1-D grid: each XCD owns 3 heads (K/V L2-resident)
//   - wave-voted skip of the online-softmax rescale (exact when skipped)
// grid: 768 = 24 heads x 32 q-blocks. block 512 = 8 waves, 16 q-rows/wave, 128-key tiles.
__global__ __launch_bounds__(512, 6) void attn_kernel(const bf16* __restrict__ Qb,
                                                      const bf16* __restrict__ Kb,
                                                      const bf16* __restrict__ Vtb,
                                                      bf16* __restrict__ ctx) {
    __shared__ bf16 Ksm[128][72];
    __shared__ bf16 Vts[64][136];
    __shared__ bf16 Psm[8][16][40];  // per-wave 16q x 32k chunk, XOR-swizzled
    const int tid = threadIdx.x, l = tid & 63, w = tid >> 6;
    const int raw = blockIdx.x;
    const int rem = (raw & 7) * 96 + (raw >> 3);  // XCD k owns heads 3k..3k+2
    const int bh = rem >> 5;
    const int qblk = rem & 31;
    const int q0 = qblk * 128;
    const bf16* Qh = Qb + (size_t)bh * SEQ * DK;
    const bf16* Kh = Kb + (size_t)bh * SEQ * DK;
    const bf16* Vth = Vtb + (size_t)bh * DK * SEQ;

    const int rsel = l & 15, csel = l >> 4;

    // Q fragments in registers (pre-scaled by 0.125*log2e in projection)
    bf16x8 qf[2];
    {
        const int qr = q0 + w * 16 + rsel;
        const int kc = csel * 8;
        qf[0] = *reinterpret_cast<const bf16x8*>(Qh + (size_t)qr * DK + kc);
        qf[1] = *reinterpret_cast<const bf16x8*>(Qh + (size_t)qr * DK + 32 + kc);
    }

    float mst[4], lst[4];
    f32x4 aco[4];
#pragma unroll
    for (int r = 0; r < 4; r++) { mst[r] = -1e30f; lst[r] = 0.f; }
#pragma unroll
    for (int f = 0; f < 4; f++) aco[f] = f32x4{0.f, 0.f, 0.f, 0.f};

    const int kr = tid >> 3, kc8 = (tid & 7) * 8;   // K staging: rows kr, kr+64
    const int vr = tid >> 4, vc8 = (tid & 15) * 8;  // Vt staging: rows vr, vr+32

    // first tile into registers
    bf16x8 kv0 = *reinterpret_cast<const bf16x8*>(Kh + (size_t)kr * DK + kc8);
    bf16x8 kv1 = *reinterpret_cast<const bf16x8*>(Kh + (size_t)(kr + 64) * DK + kc8);
    bf16x8 kv2 = *reinterpret_cast<const bf16x8*>(Vth + (size_t)vr * SEQ + vc8);
    bf16x8 kv3 = *reinterpret_cast<const bf16x8*>(Vth + (size_t)(vr + 32) * SEQ + vc8);

    constexpr int NT = SEQ / 128;
    for (int t = 0; t < NT; ++t) {
        __syncthreads();  // previous tile fully consumed
        *reinterpret_cast<bf16x8*>(&Ksm[kr][kc8]) = kv0;
        *reinterpret_cast<bf16x8*>(&Ksm[kr + 64][kc8]) = kv1;
        *reinterpret_cast<bf16x8*>(&Vts[vr][vc8]) = kv2;
        *reinterpret_cast<bf16x8*>(&Vts[vr + 32][vc8]) = kv3;
        __syncthreads();

        if (t + 1 < NT) {  // prefetch next tile into regs; lands under compute
            const int k0 = (t + 1) * 128;
            kv0 = *reinterpret_cast<const bf16x8*>(Kh + (size_t)(k0 + kr) * DK + kc8);
            kv1 = *reinterpret_cast<const bf16x8*>(Kh + (size_t)(k0 + kr + 64) * DK + kc8);
            kv2 = *reinterpret_cast<const bf16x8*>(Vth + (size_t)vr * SEQ + k0 + vc8);
            kv3 = *reinterpret_cast<const bf16x8*>(Vth + (size_t)(vr + 32) * SEQ + k0 + vc8);
        }

        // S fragments: 16 q-rows x 128 keys
        f32x4 sc[8];
#pragma unroll
        for (int f = 0; f < 8; f++) sc[f] = f32x4{0.f, 0.f, 0.f, 0.f};
#pragma unroll
        for (int kk = 0; kk < 2; kk++) {
            const int krd = kk * 32 + csel * 8;
#pragma unroll
            for (int f = 0; f < 8; f++) {
                bf16x8 kf = *reinterpret_cast<const bf16x8*>(&Ksm[f * 16 + rsel][krd]);
                sc[f] = MFMA16(qf[kk], kf, sc[f]);
            }
        }

        // online softmax (base-2 domain; scores pre-scaled)
#pragma unroll
        for (int r = 0; r < 4; r++) {
            float tm = sc[0][r];
#pragma unroll
            for (int f = 1; f < 8; f++) tm = fmaxf(tm, sc[f][r]);
            tm = fmaxf(tm, __shfl_xor(tm, 1));
            tm = fmaxf(tm, __shfl_xor(tm, 2));
            tm = fmaxf(tm, __shfl_xor(tm, 4));
            tm = fmaxf(tm, __shfl_xor(tm, 8));
            if (__any(tm > mst[r])) {  // rescale only when some row's max grew (exact skip)
                const float mnew = fmaxf(mst[r], tm);
                const float scl = __builtin_amdgcn_exp2f(mst[r] - mnew);
                mst[r] = mnew;
                lst[r] *= scl;
#pragma unroll
                for (int f = 0; f < 4; f++) aco[f][r] *= scl;
            }
            float rs = 0.f;
#pragma unroll
            for (int f = 0; f < 8; f++) {
                const float p = __builtin_amdgcn_exp2f(sc[f][r] - mst[r]);
                sc[f][r] = p;
                rs += p;
            }
            rs += __shfl_xor(rs, 1);
            rs += __shfl_xor(rs, 2);
            rs += __shfl_xor(rs, 4);
            rs += __shfl_xor(rs, 8);
            lst[r] += rs;
        }

        // four wave-local P/PV phases (32 keys each); wave-local DS ops are in-order
#pragma unroll
        for (int ph = 0; ph < 4; ph++) {
#pragma unroll
            for (int ff = 0; ff < 2; ff++) {
                const int f = ph * 2 + ff;
#pragma unroll
                for (int r = 0; r < 4; r++) {
                    const int row = csel * 4 + r;
                    Psm[w][row][(ff * 16 + rsel) ^ ((row >> 3) << 4)] = (bf16)sc[f][r];
                }
            }
            const int pcol = (csel * 8) ^ ((rsel >> 3) << 4);
            bf16x8 pf = *reinterpret_cast<const bf16x8*>(&Psm[w][rsel][pcol]);
#pragma unroll
            for (int f2 = 0; f2 < 4; f2++) {
                bf16x8 vf = *reinterpret_cast<const bf16x8*>(&Vts[f2 * 16 + rsel][ph * 32 + csel * 8]);
                aco[f2] = MFMA16(pf, vf, aco[f2]);
            }
        }
    }

    const int b = bh / NHEAD, h = bh % NHEAD;
#pragma unroll
    for (int f = 0; f < 4; f++)
#pragma unroll
        for (int r = 0; r < 4; r++) {
            const int q = q0 + w * 16 + csel * 4 + r;
            const int d = f * 16 + rsel;
            ctx[((size_t)b * SEQ + q) * D_MODEL + h * DK + d] = (bf16)(aco[f][r] / lst[r]);
        }
}

// ---------------------------------------------------------------- launcher
extern "C" void kernel_launch(void* const* d_in, const int* in_sizes, int n_in,
                              void* d_out, int out_size, void* d_ws, size_t ws_size,
                              hipStream_t stream) {
    const float* x  = (const float*)d_in[0];
    const float* Wq = (const float*)d_in[1];
    const float* bq = (const float*)d_in[2];
    const float* Wk = (const float*)d_in[3];
    const float* bk = (const float*)d_in[4];
    const float* Wv = (const float*)d_in[5];
    const float* bv = (const float*)d_in[6];
    const float* Wo = (const float*)d_in[7];
    const float* bo = (const float*)d_in[8];
    float* out = (float*)d_out;

    char* ws = (char*)d_ws;
    size_t off = 0;
    auto alloc = [&](size_t bytes) { void* p = ws + off; off += (bytes + 255) & ~(size_t)255; return p; };
    bf16* xb   = (bf16*)alloc((size_t)MROWS * 768 * 2);
    bf16* Qb   = (bf16*)alloc((size_t)BATCH * NHEAD * SEQ * DK * 2);
    bf16* Kb   = (bf16*)alloc((size_t)BATCH * NHEAD * SEQ * DK * 2);
    bf16* Vtb  = (bf16*)alloc((size_t)BATCH * NHEAD * SEQ * DK * 2);
    bf16* ctxb = (bf16*)alloc((size_t)MROWS * 768 * 2);

    const int nx = MROWS * 768;
    cvt_f32_to_bf16<<<nx / (256 * 4), 256, 0, stream>>>(x, xb, nx);

    gemm_qkv<<<dim3(MROWS / 128, 36), 256, 0, stream>>>(xb, Wq, Wk, Wv, bq, bk, bv, Qb, Kb, Vtb);

    attn_kernel<<<768, 512, 0, stream>>>(Qb, Kb, Vtb, ctxb);

    gemm_out<<<dim3(MROWS / 128, 768 / 64), 256, 0, stream>>>(ctxb, Wo, bo, out);
}

// Round 6
// 317.271 us; speedup vs baseline: 1.5793x; 1.5793x over previous
//
#include <hip/hip_runtime.h>
#include <hip/hip_bf16.h>
#include <cstdint>

typedef __bf16 bf16;
typedef bf16 bf16x8 __attribute__((ext_vector_type(8)));
typedef float f32x4 __attribute__((ext_vector_type(4)));

#define MFMA16(a, b, c) __builtin_amdgcn_mfma_f32_16x16x32_bf16((a), (b), (c), 0, 0, 0)

constexpr int D_MODEL = 768;
constexpr int NHEAD = 12;
constexpr int DK = 64;
constexpr int SEQ = 4096;
constexpr int BATCH = 2;
constexpr int MROWS = BATCH * SEQ;  // 8192
constexpr float QSCALE = 0.125f * 1.44269504089f;  // (1/sqrt(dk)) * log2(e)

// ---------------------------------------------------------------- convert x
__global__ void cvt_f32_to_bf16(const float* __restrict__ in, bf16* __restrict__ out, int n) {
    int i = (blockIdx.x * blockDim.x + threadIdx.x) * 4;
    if (i + 3 < n) {
        const float4 v = *reinterpret_cast<const float4*>(in + i);
        bf16 o0 = (bf16)v.x, o1 = (bf16)v.y, o2 = (bf16)v.z, o3 = (bf16)v.w;
        bf16 o[4] = {o0, o1, o2, o3};
        *reinterpret_cast<uint64_t*>(out + i) = *reinterpret_cast<uint64_t*>(o);
    }
}

// ---------------------------------------------------------------- fused QKV projection
__global__ __launch_bounds__(256, 2) void gemm_qkv(const bf16* __restrict__ A,
                                                   const float* __restrict__ Wq,
                                                   const float* __restrict__ Wk,
                                                   const float* __restrict__ Wv,
                                                   const float* __restrict__ bq,
                                                   const float* __restrict__ bk,
                                                   const float* __restrict__ bv,
                                                   bf16* __restrict__ Qb,
                                                   bf16* __restrict__ Kb,
                                                   bf16* __restrict__ Vtb) {
    constexpr int LDP = 88;
    __shared__ bf16 Asm[128][LDP];
    __shared__ bf16 Bsm[64][LDP];
    const int tid = threadIdx.x, lane = tid & 63, wid = tid >> 6;
    const int wm = wid >> 1, wn = wid & 1;
    const int m0 = blockIdx.x * 128;
    const int sel = blockIdx.y / 12;
    const int n0 = (blockIdx.y % 12) * 64;
    const float* Bw = sel == 0 ? Wq : (sel == 1 ? Wk : Wv);
    const float* bias = sel == 0 ? bq : (sel == 1 ? bk : bv);

    f32x4 acc[4][2];
#pragma unroll
    for (int i = 0; i < 4; i++)
#pragma unroll
        for (int j = 0; j < 2; j++) acc[i][j] = f32x4{0.f, 0.f, 0.f, 0.f};

    const int rr = tid >> 3, cc = (tid & 7) * 8;
    for (int k0 = 0; k0 < 768; k0 += 64) {
#pragma unroll
        for (int p = 0; p < 4; p++)
            *reinterpret_cast<bf16x8*>(&Asm[p * 32 + rr][cc]) =
                *reinterpret_cast<const bf16x8*>(A + (size_t)(m0 + p * 32 + rr) * 768 + k0 + cc);
#pragma unroll
        for (int p = 0; p < 2; p++) {
            const float* src = Bw + (size_t)(n0 + p * 32 + rr) * 768 + k0 + cc;
            const float4 f0 = *reinterpret_cast<const float4*>(src);
            const float4 f1 = *reinterpret_cast<const float4*>(src + 4);
            bf16x8 b8;
            b8[0] = (bf16)f0.x; b8[1] = (bf16)f0.y; b8[2] = (bf16)f0.z; b8[3] = (bf16)f0.w;
            b8[4] = (bf16)f1.x; b8[5] = (bf16)f1.y; b8[6] = (bf16)f1.z; b8[7] = (bf16)f1.w;
            *reinterpret_cast<bf16x8*>(&Bsm[p * 32 + rr][cc]) = b8;
        }
        __syncthreads();
#pragma unroll
        for (int kk = 0; kk < 64; kk += 32) {
            const int krd = kk + ((lane >> 4) << 3);
            bf16x8 af[4], bfr[2];
#pragma unroll
            for (int i = 0; i < 4; i++)
                af[i] = *reinterpret_cast<const bf16x8*>(&Asm[wm * 64 + i * 16 + (lane & 15)][krd]);
#pragma unroll
            for (int j = 0; j < 2; j++)
                bfr[j] = *reinterpret_cast<const bf16x8*>(&Bsm[wn * 32 + j * 16 + (lane & 15)][krd]);
#pragma unroll
            for (int i = 0; i < 4; i++)
#pragma unroll
                for (int j = 0; j < 2; j++) acc[i][j] = MFMA16(af[i], bfr[j], acc[i][j]);
        }
        __syncthreads();
    }

    const float scale = (sel == 0) ? QSCALE : 1.0f;
    const int rbase = m0 + wm * 64 + ((lane >> 4) << 2);
    const int cbase = n0 + wn * 32 + (lane & 15);
    bf16* obf = sel == 0 ? Qb : (sel == 1 ? Kb : Vtb);
#pragma unroll
    for (int i = 0; i < 4; i++) {
#pragma unroll
        for (int j = 0; j < 2; j++) {
            const int ncol = cbase + j * 16;
            const float bv = bias[ncol];
            const int h = ncol >> 6, d = ncol & 63;
#pragma unroll
            for (int r = 0; r < 4; r++) {
                const int mrow = rbase + i * 16 + r;
                const float v = (acc[i][j][r] + bv) * scale;
                const int b = mrow >> 12, s = mrow & 4095;
                if (sel < 2) {
                    obf[(((size_t)(b * NHEAD + h)) * SEQ + s) * DK + d] = (bf16)v;
                } else {
                    obf[(((size_t)(b * NHEAD + h)) * DK + d) * SEQ + s] = (bf16)v;
                }
            }
        }
    }
}

// ---------------------------------------------------------------- out projection GEMM
__global__ __launch_bounds__(256, 2) void gemm_out(const bf16* __restrict__ A,
                                                   const float* __restrict__ Bw,
                                                   const float* __restrict__ bias,
                                                   float* __restrict__ ofl) {
    constexpr int LDP = 88;
    __shared__ bf16 Asm[128][LDP];
    __shared__ bf16 Bsm[64][LDP];
    const int tid = threadIdx.x, lane = tid & 63, wid = tid >> 6;
    const int wm = wid >> 1, wn = wid & 1;
    const int m0 = blockIdx.x * 128, n0 = blockIdx.y * 64;

    f32x4 acc[4][2];
#pragma unroll
    for (int i = 0; i < 4; i++)
#pragma unroll
        for (int j = 0; j < 2; j++) acc[i][j] = f32x4{0.f, 0.f, 0.f, 0.f};

    const int rr = tid >> 3, cc = (tid & 7) * 8;
    for (int k0 = 0; k0 < 768; k0 += 64) {
#pragma unroll
        for (int p = 0; p < 4; p++)
            *reinterpret_cast<bf16x8*>(&Asm[p * 32 + rr][cc]) =
                *reinterpret_cast<const bf16x8*>(A + (size_t)(m0 + p * 32 + rr) * 768 + k0 + cc);
#pragma unroll
        for (int p = 0; p < 2; p++) {
            const float* src = Bw + (size_t)(n0 + p * 32 + rr) * 768 + k0 + cc;
            const float4 f0 = *reinterpret_cast<const float4*>(src);
            const float4 f1 = *reinterpret_cast<const float4*>(src + 4);
            bf16x8 b8;
            b8[0] = (bf16)f0.x; b8[1] = (bf16)f0.y; b8[2] = (bf16)f0.z; b8[3] = (bf16)f0.w;
            b8[4] = (bf16)f1.x; b8[5] = (bf16)f1.y; b8[6] = (bf16)f1.z; b8[7] = (bf16)f1.w;
            *reinterpret_cast<bf16x8*>(&Bsm[p * 32 + rr][cc]) = b8;
        }
        __syncthreads();
#pragma unroll
        for (int kk = 0; kk < 64; kk += 32) {
            const int krd = kk + ((lane >> 4) << 3);
            bf16x8 af[4], bfr[2];
#pragma unroll
            for (int i = 0; i < 4; i++)
                af[i] = *reinterpret_cast<const bf16x8*>(&Asm[wm * 64 + i * 16 + (lane & 15)][krd]);
#pragma unroll
            for (int j = 0; j < 2; j++)
                bfr[j] = *reinterpret_cast<const bf16x8*>(&Bsm[wn * 32 + j * 16 + (lane & 15)][krd]);
#pragma unroll
            for (int i = 0; i < 4; i++)
#pragma unroll
                for (int j = 0; j < 2; j++) acc[i][j] = MFMA16(af[i], bfr[j], acc[i][j]);
        }
        __syncthreads();
    }

    const int rbase = m0 + wm * 64 + ((lane >> 4) << 2);
    const int cbase = n0 + wn * 32 + (lane & 15);
#pragma unroll
    for (int i = 0; i < 4; i++) {
#pragma unroll
        for (int j = 0; j < 2; j++) {
            const int ncol = cbase + j * 16;
            const float bv = bias[ncol];
#pragma unroll
            for (int r = 0; r < 4; r++) {
                const int mrow = rbase + i * 16 + r;
                ofl[(size_t)mrow * 768 + ncol] = acc[i][j][r] + bv;
            }
        }
    }
}

// ---------------------------------------------------------------- flash attention
// R2-proven fabric + 32-key Psm (46KB LDS -> 3 blocks/CU) + register prefetch.
// bounds(512,4): VGPR cap 128 — allocator free, no spill (R5 lesson: (512,6) forced
// 40 VGPRs + ~1GB scratch spill traffic, attn 272->430us).
// grid: (32 q-blocks, 24 heads) 2-D — consecutive blocks share K/V (proven 104MB fetch).
__global__ __launch_bounds__(512, 4) void attn_kernel(const bf16* __restrict__ Qb,
                                                      const bf16* __restrict__ Kb,
                                                      const bf16* __restrict__ Vtb,
                                                      bf16* __restrict__ ctx) {
    __shared__ bf16 Ksm[128][72];
    __shared__ bf16 Vts[64][136];
    __shared__ bf16 Psm[8][16][40];  // per-wave 16q x 32k chunk, XOR-swizzled
    const int tid = threadIdx.x, l = tid & 63, w = tid >> 6;
    const int bh = blockIdx.y;
    const int q0 = blockIdx.x * 128;
    const bf16* Qh = Qb + (size_t)bh * SEQ * DK;
    const bf16* Kh = Kb + (size_t)bh * SEQ * DK;
    const bf16* Vth = Vtb + (size_t)bh * DK * SEQ;

    const int rsel = l & 15, csel = l >> 4;

    // Q fragments in registers (pre-scaled by 0.125*log2e in projection)
    bf16x8 qf[2];
    {
        const int qr = q0 + w * 16 + rsel;
        const int kc = csel * 8;
        qf[0] = *reinterpret_cast<const bf16x8*>(Qh + (size_t)qr * DK + kc);
        qf[1] = *reinterpret_cast<const bf16x8*>(Qh + (size_t)qr * DK + 32 + kc);
    }

    float mst[4], lst[4];
    f32x4 aco[4];
#pragma unroll
    for (int r = 0; r < 4; r++) { mst[r] = -1e30f; lst[r] = 0.f; }
#pragma unroll
    for (int f = 0; f < 4; f++) aco[f] = f32x4{0.f, 0.f, 0.f, 0.f};

    const int kr = tid >> 3, kc8 = (tid & 7) * 8;   // K staging: rows kr, kr+64
    const int vr = tid >> 4, vc8 = (tid & 15) * 8;  // Vt staging: rows vr, vr+32

    // first tile into registers
    bf16x8 kv0 = *reinterpret_cast<const bf16x8*>(Kh + (size_t)kr * DK + kc8);
    bf16x8 kv1 = *reinterpret_cast<const bf16x8*>(Kh + (size_t)(kr + 64) * DK + kc8);
    bf16x8 kv2 = *reinterpret_cast<const bf16x8*>(Vth + (size_t)vr * SEQ + vc8);
    bf16x8 kv3 = *reinterpret_cast<const bf16x8*>(Vth + (size_t)(vr + 32) * SEQ + vc8);

    constexpr int NT = SEQ / 128;
    for (int t = 0; t < NT; ++t) {
        __syncthreads();  // previous tile fully consumed
        *reinterpret_cast<bf16x8*>(&Ksm[kr][kc8]) = kv0;
        *reinterpret_cast<bf16x8*>(&Ksm[kr + 64][kc8]) = kv1;
        *reinterpret_cast<bf16x8*>(&Vts[vr][vc8]) = kv2;
        *reinterpret_cast<bf16x8*>(&Vts[vr + 32][vc8]) = kv3;
        __syncthreads();

        if (t + 1 < NT) {  // prefetch next tile into regs; lands under compute
            const int k0 = (t + 1) * 128;
            kv0 = *reinterpret_cast<const bf16x8*>(Kh + (size_t)(k0 + kr) * DK + kc8);
            kv1 = *reinterpret_cast<const bf16x8*>(Kh + (size_t)(k0 + kr + 64) * DK + kc8);
            kv2 = *reinterpret_cast<const bf16x8*>(Vth + (size_t)vr * SEQ + k0 + vc8);
            kv3 = *reinterpret_cast<const bf16x8*>(Vth + (size_t)(vr + 32) * SEQ + k0 + vc8);
        }

        // S fragments: 16 q-rows x 128 keys
        f32x4 sc[8];
#pragma unroll
        for (int f = 0; f < 8; f++) sc[f] = f32x4{0.f, 0.f, 0.f, 0.f};
#pragma unroll
        for (int kk = 0; kk < 2; kk++) {
            const int krd = kk * 32 + csel * 8;
#pragma unroll
            for (int f = 0; f < 8; f++) {
                bf16x8 kf = *reinterpret_cast<const bf16x8*>(&Ksm[f * 16 + rsel][krd]);
                sc[f] = MFMA16(qf[kk], kf, sc[f]);
            }
        }

        // online softmax (base-2 domain; scores pre-scaled)
#pragma unroll
        for (int r = 0; r < 4; r++) {
            float tm = sc[0][r];
#pragma unroll
            for (int f = 1; f < 8; f++) tm = fmaxf(tm, sc[f][r]);
            tm = fmaxf(tm, __shfl_xor(tm, 1));
            tm = fmaxf(tm, __shfl_xor(tm, 2));
            tm = fmaxf(tm, __shfl_xor(tm, 4));
            tm = fmaxf(tm, __shfl_xor(tm, 8));
            if (__any(tm > mst[r])) {  // rescale only when some row's max grew (exact skip)
                const float mnew = fmaxf(mst[r], tm);
                const float scl = __builtin_amdgcn_exp2f(mst[r] - mnew);
                mst[r] = mnew;
                lst[r] *= scl;
#pragma unroll
                for (int f = 0; f < 4; f++) aco[f][r] *= scl;
            }
            float rs = 0.f;
#pragma unroll
            for (int f = 0; f < 8; f++) {
                const float p = __builtin_amdgcn_exp2f(sc[f][r] - mst[r]);
                sc[f][r] = p;
                rs += p;
            }
            rs += __shfl_xor(rs, 1);
            rs += __shfl_xor(rs, 2);
            rs += __shfl_xor(rs, 4);
            rs += __shfl_xor(rs, 8);
            lst[r] += rs;
        }

        // four wave-local P/PV phases (32 keys each); wave-local DS ops are in-order
#pragma unroll
        for (int ph = 0; ph < 4; ph++) {
#pragma unroll
            for (int ff = 0; ff < 2; ff++) {
                const int f = ph * 2 + ff;
#pragma unroll
                for (int r = 0; r < 4; r++) {
                    const int row = csel * 4 + r;
                    Psm[w][row][(ff * 16 + rsel) ^ ((row >> 3) << 4)] = (bf16)sc[f][r];
                }
            }
            const int pcol = (csel * 8) ^ ((rsel >> 3) << 4);
            bf16x8 pf = *reinterpret_cast<const bf16x8*>(&Psm[w][rsel][pcol]);
#pragma unroll
            for (int f2 = 0; f2 < 4; f2++) {
                bf16x8 vf = *reinterpret_cast<const bf16x8*>(&Vts[f2 * 16 + rsel][ph * 32 + csel * 8]);
                aco[f2] = MFMA16(pf, vf, aco[f2]);
            }
        }
    }

    const int b = bh / NHEAD, h = bh % NHEAD;
#pragma unroll
    for (int f = 0; f < 4; f++)
#pragma unroll
        for (int r = 0; r < 4; r++) {
            const int q = q0 + w * 16 + csel * 4 + r;
            const int d = f * 16 + rsel;
            ctx[((size_t)b * SEQ + q) * D_MODEL + h * DK + d] = (bf16)(aco[f][r] / lst[r]);
        }
}

// ---------------------------------------------------------------- launcher
extern "C" void kernel_launch(void* const* d_in, const int* in_sizes, int n_in,
                              void* d_out, int out_size, void* d_ws, size_t ws_size,
                              hipStream_t stream) {
    const float* x  = (const float*)d_in[0];
    const float* Wq = (const float*)d_in[1];
    const float* bq = (const float*)d_in[2];
    const float* Wk = (const float*)d_in[3];
    const float* bk = (const float*)d_in[4];
    const float* Wv = (const float*)d_in[5];
    const float* bv = (const float*)d_in[6];
    const float* Wo = (const float*)d_in[7];
    const float* bo = (const float*)d_in[8];
    float* out = (float*)d_out;

    char* ws = (char*)d_ws;
    size_t off = 0;
    auto alloc = [&](size_t bytes) { void* p = ws + off; off += (bytes + 255) & ~(size_t)255; return p; };
    bf16* xb   = (bf16*)alloc((size_t)MROWS * 768 * 2);
    bf16* Qb   = (bf16*)alloc((size_t)BATCH * NHEAD * SEQ * DK * 2);
    bf16* Kb   = (bf16*)alloc((size_t)BATCH * NHEAD * SEQ * DK * 2);
    bf16* Vtb  = (bf16*)alloc((size_t)BATCH * NHEAD * SEQ * DK * 2);
    bf16* ctxb = (bf16*)alloc((size_t)MROWS * 768 * 2);

    const int nx = MROWS * 768;
    cvt_f32_to_bf16<<<nx / (256 * 4), 256, 0, stream>>>(x, xb, nx);

    gemm_qkv<<<dim3(MROWS / 128, 36), 256, 0, stream>>>(xb, Wq, Wk, Wv, bq, bk, bv, Qb, Kb, Vtb);

    attn_kernel<<<dim3(SEQ / 128, BATCH * NHEAD), 512, 0, stream>>>(Qb, Kb, Vtb, ctxb);

    gemm_out<<<dim3(MROWS / 128, 768 / 64), 256, 0, stream>>>(ctxb, Wo, bo, out);
}

// Round 7
// 275.948 us; speedup vs baseline: 1.8158x; 1.1498x over previous
//
#include <hip/hip_runtime.h>
#include <hip/hip_bf16.h>
#include <cstdint>

typedef __bf16 bf16;
typedef bf16 bf16x8 __attribute__((ext_vector_type(8)));
typedef float f32x4 __attribute__((ext_vector_type(4)));

#define MFMA16(a, b, c) __builtin_amdgcn_mfma_f32_16x16x32_bf16((a), (b), (c), 0, 0, 0)

constexpr int D_MODEL = 768;
constexpr int NHEAD = 12;
constexpr int DK = 64;
constexpr int SEQ = 4096;
constexpr int BATCH = 2;
constexpr int MROWS = BATCH * SEQ;  // 8192
constexpr float QSCALE = 0.125f * 1.44269504089f;  // (1/sqrt(dk)) * log2(e)

// ---------------------------------------------------------------- convert x
__global__ void cvt_f32_to_bf16(const float* __restrict__ in, bf16* __restrict__ out, int n) {
    int i = (blockIdx.x * blockDim.x + threadIdx.x) * 4;
    if (i + 3 < n) {
        const float4 v = *reinterpret_cast<const float4*>(in + i);
        bf16 o0 = (bf16)v.x, o1 = (bf16)v.y, o2 = (bf16)v.z, o3 = (bf16)v.w;
        bf16 o[4] = {o0, o1, o2, o3};
        *reinterpret_cast<uint64_t*>(out + i) = *reinterpret_cast<uint64_t*>(o);
    }
}

// ---------------------------------------------------------------- fused QKV projection
__global__ __launch_bounds__(256, 2) void gemm_qkv(const bf16* __restrict__ A,
                                                   const float* __restrict__ Wq,
                                                   const float* __restrict__ Wk,
                                                   const float* __restrict__ Wv,
                                                   const float* __restrict__ bq,
                                                   const float* __restrict__ bk,
                                                   const float* __restrict__ bv,
                                                   bf16* __restrict__ Qb,
                                                   bf16* __restrict__ Kb,
                                                   bf16* __restrict__ Vtb) {
    constexpr int LDP = 88;
    __shared__ bf16 Asm[128][LDP];
    __shared__ bf16 Bsm[64][LDP];
    const int tid = threadIdx.x, lane = tid & 63, wid = tid >> 6;
    const int wm = wid >> 1, wn = wid & 1;
    const int m0 = blockIdx.x * 128;
    const int sel = blockIdx.y / 12;
    const int n0 = (blockIdx.y % 12) * 64;
    const float* Bw = sel == 0 ? Wq : (sel == 1 ? Wk : Wv);
    const float* bias = sel == 0 ? bq : (sel == 1 ? bk : bv);

    f32x4 acc[4][2];
#pragma unroll
    for (int i = 0; i < 4; i++)
#pragma unroll
        for (int j = 0; j < 2; j++) acc[i][j] = f32x4{0.f, 0.f, 0.f, 0.f};

    const int rr = tid >> 3, cc = (tid & 7) * 8;
    for (int k0 = 0; k0 < 768; k0 += 64) {
#pragma unroll
        for (int p = 0; p < 4; p++)
            *reinterpret_cast<bf16x8*>(&Asm[p * 32 + rr][cc]) =
                *reinterpret_cast<const bf16x8*>(A + (size_t)(m0 + p * 32 + rr) * 768 + k0 + cc);
#pragma unroll
        for (int p = 0; p < 2; p++) {
            const float* src = Bw + (size_t)(n0 + p * 32 + rr) * 768 + k0 + cc;
            const float4 f0 = *reinterpret_cast<const float4*>(src);
            const float4 f1 = *reinterpret_cast<const float4*>(src + 4);
            bf16x8 b8;
            b8[0] = (bf16)f0.x; b8[1] = (bf16)f0.y; b8[2] = (bf16)f0.z; b8[3] = (bf16)f0.w;
            b8[4] = (bf16)f1.x; b8[5] = (bf16)f1.y; b8[6] = (bf16)f1.z; b8[7] = (bf16)f1.w;
            *reinterpret_cast<bf16x8*>(&Bsm[p * 32 + rr][cc]) = b8;
        }
        __syncthreads();
#pragma unroll
        for (int kk = 0; kk < 64; kk += 32) {
            const int krd = kk + ((lane >> 4) << 3);
            bf16x8 af[4], bfr[2];
#pragma unroll
            for (int i = 0; i < 4; i++)
                af[i] = *reinterpret_cast<const bf16x8*>(&Asm[wm * 64 + i * 16 + (lane & 15)][krd]);
#pragma unroll
            for (int j = 0; j < 2; j++)
                bfr[j] = *reinterpret_cast<const bf16x8*>(&Bsm[wn * 32 + j * 16 + (lane & 15)][krd]);
#pragma unroll
            for (int i = 0; i < 4; i++)
#pragma unroll
                for (int j = 0; j < 2; j++) acc[i][j] = MFMA16(af[i], bfr[j], acc[i][j]);
        }
        __syncthreads();
    }

    const float scale = (sel == 0) ? QSCALE : 1.0f;
    const int rbase = m0 + wm * 64 + ((lane >> 4) << 2);
    const int cbase = n0 + wn * 32 + (lane & 15);
    bf16* obf = sel == 0 ? Qb : (sel == 1 ? Kb : Vtb);
#pragma unroll
    for (int i = 0; i < 4; i++) {
#pragma unroll
        for (int j = 0; j < 2; j++) {
            const int ncol = cbase + j * 16;
            const float bv = bias[ncol];
            const int h = ncol >> 6, d = ncol & 63;
#pragma unroll
            for (int r = 0; r < 4; r++) {
                const int mrow = rbase + i * 16 + r;
                const float v = (acc[i][j][r] + bv) * scale;
                const int b = mrow >> 12, s = mrow & 4095;
                if (sel < 2) {
                    obf[(((size_t)(b * NHEAD + h)) * SEQ + s) * DK + d] = (bf16)v;
                } else {
                    obf[(((size_t)(b * NHEAD + h)) * DK + d) * SEQ + s] = (bf16)v;
                }
            }
        }
    }
}

// ---------------------------------------------------------------- out projection GEMM
__global__ __launch_bounds__(256, 2) void gemm_out(const bf16* __restrict__ A,
                                                   const float* __restrict__ Bw,
                                                   const float* __restrict__ bias,
                                                   float* __restrict__ ofl) {
    constexpr int LDP = 88;
    __shared__ bf16 Asm[128][LDP];
    __shared__ bf16 Bsm[64][LDP];
    const int tid = threadIdx.x, lane = tid & 63, wid = tid >> 6;
    const int wm = wid >> 1, wn = wid & 1;
    const int m0 = blockIdx.x * 128, n0 = blockIdx.y * 64;

    f32x4 acc[4][2];
#pragma unroll
    for (int i = 0; i < 4; i++)
#pragma unroll
        for (int j = 0; j < 2; j++) acc[i][j] = f32x4{0.f, 0.f, 0.f, 0.f};

    const int rr = tid >> 3, cc = (tid & 7) * 8;
    for (int k0 = 0; k0 < 768; k0 += 64) {
#pragma unroll
        for (int p = 0; p < 4; p++)
            *reinterpret_cast<bf16x8*>(&Asm[p * 32 + rr][cc]) =
                *reinterpret_cast<const bf16x8*>(A + (size_t)(m0 + p * 32 + rr) * 768 + k0 + cc);
#pragma unroll
        for (int p = 0; p < 2; p++) {
            const float* src = Bw + (size_t)(n0 + p * 32 + rr) * 768 + k0 + cc;
            const float4 f0 = *reinterpret_cast<const float4*>(src);
            const float4 f1 = *reinterpret_cast<const float4*>(src + 4);
            bf16x8 b8;
            b8[0] = (bf16)f0.x; b8[1] = (bf16)f0.y; b8[2] = (bf16)f0.z; b8[3] = (bf16)f0.w;
            b8[4] = (bf16)f1.x; b8[5] = (bf16)f1.y; b8[6] = (bf16)f1.z; b8[7] = (bf16)f1.w;
            *reinterpret_cast<bf16x8*>(&Bsm[p * 32 + rr][cc]) = b8;
        }
        __syncthreads();
#pragma unroll
        for (int kk = 0; kk < 64; kk += 32) {
            const int krd = kk + ((lane >> 4) << 3);
            bf16x8 af[4], bfr[2];
#pragma unroll
            for (int i = 0; i < 4; i++)
                af[i] = *reinterpret_cast<const bf16x8*>(&Asm[wm * 64 + i * 16 + (lane & 15)][krd]);
#pragma unroll
            for (int j = 0; j < 2; j++)
                bfr[j] = *reinterpret_cast<const bf16x8*>(&Bsm[wn * 32 + j * 16 + (lane & 15)][krd]);
#pragma unroll
            for (int i = 0; i < 4; i++)
#pragma unroll
                for (int j = 0; j < 2; j++) acc[i][j] = MFMA16(af[i], bfr[j], acc[i][j]);
        }
        __syncthreads();
    }

    const int rbase = m0 + wm * 64 + ((lane >> 4) << 2);
    const int cbase = n0 + wn * 32 + (lane & 15);
#pragma unroll
    for (int i = 0; i < 4; i++) {
#pragma unroll
        for (int j = 0; j < 2; j++) {
            const int ncol = cbase + j * 16;
            const float bv = bias[ncol];
#pragma unroll
            for (int r = 0; r < 4; r++) {
                const int mrow = rbase + i * 16 + r;
                ofl[(size_t)mrow * 768 + ncol] = acc[i][j][r] + bv;
            }
        }
    }
}

// ---------------------------------------------------------------- flash attention
// R6-proven fabric (260us) + softmax overhead reduction:
//   - ONE wave-shared running max m (softmax invariant to any m >= row max; bf16
//     relative error is scale-invariant) -> 1 butterfly instead of 4 serial chains
//   - defer-rescale THR=8 (T13), wave-uniform scalar gate
//   - row-sums computed by MFMA via ones-row 64 of Vts (rows 65-79 zero):
//     aco_x accumulates sum_k P[q][k]; rescale covers it automatically; denominator
//     now summed from the rounded bf16 P (num/denom consistency)
__global__ __launch_bounds__(512, 4) void attn_kernel(const bf16* __restrict__ Qb,
                                                      const bf16* __restrict__ Kb,
                                                      const bf16* __restrict__ Vtb,
                                                      bf16* __restrict__ ctx) {
    __shared__ bf16 Ksm[128][72];
    __shared__ bf16 Vts[80][136];    // rows 0-63: V^T; row 64: ones; 65-79: zeros
    __shared__ bf16 Psm[8][16][40];  // per-wave 16q x 32k chunk, XOR-swizzled
    const int tid = threadIdx.x, l = tid & 63, w = tid >> 6;
    const int bh = blockIdx.y;
    const int q0 = blockIdx.x * 128;
    const bf16* Qh = Qb + (size_t)bh * SEQ * DK;
    const bf16* Kh = Kb + (size_t)bh * SEQ * DK;
    const bf16* Vth = Vtb + (size_t)bh * DK * SEQ;

    const int rsel = l & 15, csel = l >> 4;

    // init ones/zero rows (64..79) of Vts once
    {
        const int irow = 64 + (tid >> 5);
        const bf16 val = (irow == 64) ? (bf16)1.0f : (bf16)0.0f;
        for (int c = tid & 31; c < 136; c += 32) Vts[irow][c] = val;
    }

    // Q fragments in registers (pre-scaled by 0.125*log2e in projection)
    bf16x8 qf[2];
    {
        const int qr = q0 + w * 16 + rsel;
        const int kc = csel * 8;
        qf[0] = *reinterpret_cast<const bf16x8*>(Qh + (size_t)qr * DK + kc);
        qf[1] = *reinterpret_cast<const bf16x8*>(Qh + (size_t)qr * DK + 32 + kc);
    }

    float m = -1e30f;
    f32x4 aco[4], aco_x;
#pragma unroll
    for (int f = 0; f < 4; f++) aco[f] = f32x4{0.f, 0.f, 0.f, 0.f};
    aco_x = f32x4{0.f, 0.f, 0.f, 0.f};

    const int kr = tid >> 3, kc8 = (tid & 7) * 8;   // K staging: rows kr, kr+64
    const int vr = tid >> 4, vc8 = (tid & 15) * 8;  // Vt staging: rows vr, vr+32

    // first tile into registers
    bf16x8 kv0 = *reinterpret_cast<const bf16x8*>(Kh + (size_t)kr * DK + kc8);
    bf16x8 kv1 = *reinterpret_cast<const bf16x8*>(Kh + (size_t)(kr + 64) * DK + kc8);
    bf16x8 kv2 = *reinterpret_cast<const bf16x8*>(Vth + (size_t)vr * SEQ + vc8);
    bf16x8 kv3 = *reinterpret_cast<const bf16x8*>(Vth + (size_t)(vr + 32) * SEQ + vc8);

    constexpr int NT = SEQ / 128;
    for (int t = 0; t < NT; ++t) {
        __syncthreads();  // previous tile fully consumed (also covers ones-row init)
        *reinterpret_cast<bf16x8*>(&Ksm[kr][kc8]) = kv0;
        *reinterpret_cast<bf16x8*>(&Ksm[kr + 64][kc8]) = kv1;
        *reinterpret_cast<bf16x8*>(&Vts[vr][vc8]) = kv2;
        *reinterpret_cast<bf16x8*>(&Vts[vr + 32][vc8]) = kv3;
        __syncthreads();

        if (t + 1 < NT) {  // prefetch next tile into regs; lands under compute
            const int k0 = (t + 1) * 128;
            kv0 = *reinterpret_cast<const bf16x8*>(Kh + (size_t)(k0 + kr) * DK + kc8);
            kv1 = *reinterpret_cast<const bf16x8*>(Kh + (size_t)(k0 + kr + 64) * DK + kc8);
            kv2 = *reinterpret_cast<const bf16x8*>(Vth + (size_t)vr * SEQ + k0 + vc8);
            kv3 = *reinterpret_cast<const bf16x8*>(Vth + (size_t)(vr + 32) * SEQ + k0 + vc8);
        }

        // S fragments: 16 q-rows x 128 keys
        f32x4 sc[8];
#pragma unroll
        for (int f = 0; f < 8; f++) sc[f] = f32x4{0.f, 0.f, 0.f, 0.f};
#pragma unroll
        for (int kk = 0; kk < 2; kk++) {
            const int krd = kk * 32 + csel * 8;
#pragma unroll
            for (int f = 0; f < 8; f++) {
                bf16x8 kf = *reinterpret_cast<const bf16x8*>(&Ksm[f * 16 + rsel][krd]);
                sc[f] = MFMA16(qf[kk], kf, sc[f]);
            }
        }

        // wave-shared max: in-register 32-max + 6-step butterfly (one chain)
        float tm = sc[0][0];
#pragma unroll
        for (int f = 0; f < 8; f++)
#pragma unroll
            for (int r = 0; r < 4; r++) tm = fmaxf(tm, sc[f][r]);
        tm = fmaxf(tm, __shfl_xor(tm, 1));
        tm = fmaxf(tm, __shfl_xor(tm, 2));
        tm = fmaxf(tm, __shfl_xor(tm, 4));
        tm = fmaxf(tm, __shfl_xor(tm, 8));
        tm = fmaxf(tm, __shfl_xor(tm, 16));
        tm = fmaxf(tm, __shfl_xor(tm, 32));

        // defer-rescale (THR=8, log2 domain); wave-uniform scalar branch
        if (tm - m > 8.f) {
            const float scl = __builtin_amdgcn_exp2f(m - tm);
            m = tm;
#pragma unroll
            for (int f = 0; f < 4; f++)
#pragma unroll
                for (int r = 0; r < 4; r++) aco[f][r] *= scl;
#pragma unroll
            for (int r = 0; r < 4; r++) aco_x[r] *= scl;
        }

        // P = exp2(S - m) -> bf16 (denominator comes from the MFMA ones-row)
#pragma unroll
        for (int f = 0; f < 8; f++)
#pragma unroll
            for (int r = 0; r < 4; r++)
                sc[f][r] = __builtin_amdgcn_exp2f(sc[f][r] - m);

        // four wave-local P/PV phases (32 keys each); wave-local DS ops are in-order
#pragma unroll
        for (int ph = 0; ph < 4; ph++) {
#pragma unroll
            for (int ff = 0; ff < 2; ff++) {
                const int f = ph * 2 + ff;
#pragma unroll
                for (int r = 0; r < 4; r++) {
                    const int row = csel * 4 + r;
                    Psm[w][row][(ff * 16 + rsel) ^ ((row >> 3) << 4)] = (bf16)sc[f][r];
                }
            }
            const int pcol = (csel * 8) ^ ((rsel >> 3) << 4);
            bf16x8 pf = *reinterpret_cast<const bf16x8*>(&Psm[w][rsel][pcol]);
#pragma unroll
            for (int f2 = 0; f2 < 4; f2++) {
                bf16x8 vf = *reinterpret_cast<const bf16x8*>(&Vts[f2 * 16 + rsel][ph * 32 + csel * 8]);
                aco[f2] = MFMA16(pf, vf, aco[f2]);
            }
            // ones-row MFMA: accumulates row sums of P into aco_x
            bf16x8 vfx = *reinterpret_cast<const bf16x8*>(&Vts[64 + rsel][ph * 32 + csel * 8]);
            aco_x = MFMA16(pf, vfx, aco_x);
        }
    }

    // epilogue: lst[q] lives in lanes rsel==0 of each csel group (col 0 of aco_x)
    float inv[4];
#pragma unroll
    for (int r = 0; r < 4; r++) inv[r] = 1.0f / __shfl(aco_x[r], l & 48);

    const int b = bh / NHEAD, h = bh % NHEAD;
#pragma unroll
    for (int f = 0; f < 4; f++)
#pragma unroll
        for (int r = 0; r < 4; r++) {
            const int q = q0 + w * 16 + csel * 4 + r;
            const int d = f * 16 + rsel;
            ctx[((size_t)b * SEQ + q) * D_MODEL + h * DK + d] = (bf16)(aco[f][r] * inv[r]);
        }
}

// ---------------------------------------------------------------- launcher
extern "C" void kernel_launch(void* const* d_in, const int* in_sizes, int n_in,
                              void* d_out, int out_size, void* d_ws, size_t ws_size,
                              hipStream_t stream) {
    const float* x  = (const float*)d_in[0];
    const float* Wq = (const float*)d_in[1];
    const float* bq = (const float*)d_in[2];
    const float* Wk = (const float*)d_in[3];
    const float* bk = (const float*)d_in[4];
    const float* Wv = (const float*)d_in[5];
    const float* bv = (const float*)d_in[6];
    const float* Wo = (const float*)d_in[7];
    const float* bo = (const float*)d_in[8];
    float* out = (float*)d_out;

    char* ws = (char*)d_ws;
    size_t off = 0;
    auto alloc = [&](size_t bytes) { void* p = ws + off; off += (bytes + 255) & ~(size_t)255; return p; };
    bf16* xb   = (bf16*)alloc((size_t)MROWS * 768 * 2);
    bf16* Qb   = (bf16*)alloc((size_t)BATCH * NHEAD * SEQ * DK * 2);
    bf16* Kb   = (bf16*)alloc((size_t)BATCH * NHEAD * SEQ * DK * 2);
    bf16* Vtb  = (bf16*)alloc((size_t)BATCH * NHEAD * SEQ * DK * 2);
    bf16* ctxb = (bf16*)alloc((size_t)MROWS * 768 * 2);

    const int nx = MROWS * 768;
    cvt_f32_to_bf16<<<nx / (256 * 4), 256, 0, stream>>>(x, xb, nx);

    gemm_qkv<<<dim3(MROWS / 128, 36), 256, 0, stream>>>(xb, Wq, Wk, Wv, bq, bk, bv, Qb, Kb, Vtb);

    attn_kernel<<<dim3(SEQ / 128, BATCH * NHEAD), 512, 0, stream>>>(Qb, Kb, Vtb, ctxb);

    gemm_out<<<dim3(MROWS / 128, 768 / 64), 256, 0, stream>>>(ctxb, Wo, bo, out);
}